// Round 7
// baseline (154.177 us; speedup 1.0000x reference)
//
#include <hip/hip_runtime.h>
#include <hip/hip_bf16.h>
#include <hip/hip_fp16.h>
#include <cmath>

#define NF 64
#define GRP 8
#define CG 8
#define KK 9
#define HH 128
#define WWID 128
#define BB 4
#define HWSZ (HH * WWID)
#define C_OM 216
#define OMS 292   // halfs per pixel in om LDS (8B-aligned quads, 2-way-free banks)

typedef __attribute__((ext_vector_type(8))) short bf16x8;
typedef __attribute__((ext_vector_type(4))) float f32x4;
typedef __attribute__((ext_vector_type(16))) float f32x16;

__device__ inline unsigned short f2bf(float f) {
    union { float f; unsigned u; } x; x.f = f;
    unsigned r = x.u + 0x7fff + ((x.u >> 16) & 1);   // RNE
    return (unsigned short)(r >> 16);
}
__device__ inline float bf2f(unsigned short s) {
    union { unsigned u; float f; } x; x.u = ((unsigned)s) << 16; return x.f;
}

// ---------------------------------------------------------------------------
// NCHW fp32 (nbr ++ ref) -> NHWC bf16 [B][H][W][128]  +  group-major
// gather buffer gm[B][G][H][W][8ch] bf16 (16B records).
// ---------------------------------------------------------------------------
__global__ __launch_bounds__(256) void to_nhwc_kernel(
    const float* __restrict__ nbr, const float* __restrict__ ref,
    unsigned short* __restrict__ out, unsigned short* __restrict__ gm)
{
    __shared__ unsigned short lds[64 * 136];
    const int tid = threadIdx.x, blk = blockIdx.x;
    const int b = blk >> 8, rem = blk & 255, y = rem >> 1, x0 = (rem & 1) * 64;
    const size_t rowoff = (size_t)y * WWID + x0;

    for (int it = 0; it < 32; ++it) {
        int idx = it * 256 + tid;
        int c = idx >> 6, p = idx & 63;
        const float* src = (c < NF) ? (nbr + (size_t)(b * NF + c) * HWSZ)
                                    : (ref + (size_t)(b * NF + c - NF) * HWSZ);
        lds[p * 136 + c] = f2bf(src[rowoff + p]);
    }
    __syncthreads();
    const int p = tid >> 2, c0 = (tid & 3) * 32;
    unsigned short* dst = out + ((size_t)b * HWSZ + rowoff + p) * 128 + c0;
#pragma unroll
    for (int i = 0; i < 8; ++i)
        *(int2*)(dst + i * 4) = *(const int2*)&lds[p * 136 + c0 + i * 4];
    if (c0 < 64) {
#pragma unroll
        for (int gi = 0; gi < 4; ++gi) {
            const int g = (c0 >> 3) + gi;
            *(int4*)(gm + (((size_t)(b * 8 + g)) * HWSZ + rowoff + p) * 8) =
                *(const int4*)&lds[p * 136 + g * 8];
        }
    }
}

// ---------------------------------------------------------------------------
// All weight repacks, one launch.
// wf1: conv1 A-frags, 16x16x32 layout (CIN=128, COUT=64, MT=4):  73728
// wf2: om A-frags, 32x32x16 layout [ks(36)][mt(7)][lane][j]:    129024
// wdf: dcn A-frags, 32x32x16 layout [ks(36)][mt(2)][lane][j]:    36864
// ---------------------------------------------------------------------------
__global__ void repack_all_kernel(const float* __restrict__ w1,
                                  const float* __restrict__ wom,
                                  const float* __restrict__ wdcn,
                                  unsigned short* __restrict__ wf1,
                                  unsigned short* __restrict__ wf2,
                                  unsigned short* __restrict__ wdf)
{
    int idx = blockIdx.x * 256 + threadIdx.x;
    if (idx < 73728) {   // conv1: 16x16x32 A: row=lane&15, k=(lane>>4)*8+j
        int j = idx & 7, lane = (idx >> 3) & 63, t = idx >> 9;
        int mt = t % 4, kt = t / 4;
        int c0 = (kt / 9) * 32, tap = kt - (kt / 9) * 9;
        int cout = mt * 16 + (lane & 15);
        int cin = c0 + ((lane >> 4) * 8) + j;
        wf1[idx] = f2bf(w1[((size_t)cout * 128 + cin) * KK + tap]);
        return;
    }
    idx -= 73728;
    if (idx < 129024) {  // om: 32x32x16 A: row=lane&31, k=(lane>>5)*8+j
        int j = idx & 7, lane = (idx >> 3) & 63, t = idx >> 9;
        int mt = t % 7, ks = t / 7;
        int cout = mt * 32 + (lane & 31);
        int K = ks * 16 + (lane >> 5) * 8 + j;
        int kb32 = K >> 5;
        int c032 = kb32 / 9, tap = kb32 - c032 * 9;
        int cin = c032 * 32 + (K & 31);
        float v = (cout < C_OM) ? wom[((size_t)cout * 64 + cin) * KK + tap] : 0.f;
        wf2[idx] = f2bf(v);
        return;
    }
    idx -= 129024;
    if (idx < 36864) {   // dcn: 32x32x16 A over K=(g*9+kt)*8+c
        int j = idx & 7, lane = (idx >> 3) & 63, t = idx >> 9;
        int mt = t & 1, ks = t >> 1;
        int cout = mt * 32 + (lane & 31);
        int K = ks * 16 + (lane >> 5) * 8 + j;
        int gk = K >> 3, c = K & 7;
        int g = gk / 9, kt = gk - g * 9;
        wdf[idx] = f2bf(wdcn[((size_t)cout * NF + g * 8 + c) * 9 + kt]);
    }
}

// ---------------------------------------------------------------------------
// Implicit-GEMM 3x3 conv (conv1) via mfma_f32_16x16x32_bf16. (unchanged)
// ---------------------------------------------------------------------------
template <int CIN, int COUT, bool LRELU, int NT>
__global__ __launch_bounds__(256) void conv_mfma_kernel(
    const unsigned short* __restrict__ in,
    const unsigned short* __restrict__ wf,
    const float* __restrict__ bias,
    unsigned short* __restrict__ dst)
{
    const int tid = threadIdx.x;
    const int lane = tid & 63;
    const int wv = tid >> 6;
    const int ng = blockIdx.x * 4 + wv;
    constexpr int SEG = 128 / (16 * NT);
    const int x0 = (ng % SEG) * (16 * NT);
    const int y  = (ng / SEG) % 128;
    const int b  = ng / (SEG * 128);
    const int ln = lane & 15, kb = lane >> 4;

    f32x4 acc[4][NT];
#pragma unroll
    for (int i = 0; i < 4; ++i)
#pragma unroll
        for (int j = 0; j < NT; ++j) acc[i][j] = f32x4{0.f, 0.f, 0.f, 0.f};

    const unsigned short* inb = in + (size_t)b * HWSZ * CIN + (size_t)kb * 8;

    for (int c0 = 0; c0 < CIN; c0 += 32) {
#pragma unroll
        for (int tap = 0; tap < 9; ++tap) {
            const int ky = tap / 3, kx = tap % 3;
            const int yy = y + ky - 1;
            const bool rowv = (unsigned)yy < (unsigned)HH;
            const int yc = rowv ? yy : 0;
            const unsigned short* rowp = inb + (size_t)yc * WWID * CIN + c0;
            bf16x8 bfrag[NT];
#pragma unroll
            for (int nt = 0; nt < NT; ++nt) {
                int xx = x0 + nt * 16 + ln + kx - 1;
                bool v = rowv && ((unsigned)xx < (unsigned)WWID);
                int xc = v ? xx : 0;
                int4 t = *(const int4*)(rowp + (size_t)xc * CIN);
                if (!v) { t.x = 0; t.y = 0; t.z = 0; t.w = 0; }
                bfrag[nt] = *(bf16x8*)&t;
            }
            const int kt = (c0 / 32) * 9 + tap;
            const bf16x8* af = (const bf16x8*)wf + (size_t)kt * 4 * 64 + lane;
            bf16x8 afrag[4];
#pragma unroll
            for (int mt = 0; mt < 4; ++mt) afrag[mt] = af[(size_t)mt * 64];
#pragma unroll
            for (int mt = 0; mt < 4; ++mt)
#pragma unroll
                for (int nt = 0; nt < NT; ++nt)
                    acc[mt][nt] = __builtin_amdgcn_mfma_f32_16x16x32_bf16(
                        afrag[mt], bfrag[nt], acc[mt][nt], 0, 0, 0);
        }
    }

#pragma unroll
    for (int mt = 0; mt < 4; ++mt) {
        const int cout = mt * 16 + kb * 4;
        const float b0 = bias[cout], b1 = bias[cout + 1];
        const float b2 = bias[cout + 2], b3 = bias[cout + 3];
#pragma unroll
        for (int nt = 0; nt < NT; ++nt) {
            const int px = x0 + nt * 16 + ln;
            const size_t pix = (size_t)b * HWSZ + (size_t)y * WWID + px;
            f32x4 v = acc[mt][nt];
            v[0] += b0; v[1] += b1; v[2] += b2; v[3] += b3;
            if (LRELU) {
#pragma unroll
                for (int r = 0; r < 4; ++r) v[r] = (v[r] >= 0.f) ? v[r] : 0.1f * v[r];
            }
            int2 pk;
            pk.x = (int)f2bf(v[0]) | ((int)f2bf(v[1]) << 16);
            pk.y = (int)f2bf(v[2]) | ((int)f2bf(v[3]) << 16);
            *(int2*)(dst + pix * COUT + cout) = pk;
        }
    }
}

// ---------------------------------------------------------------------------
// FUSED conv_om + DCN, 32x32x16 MFMA. Block = 256 thr / 4 waves / 64 px.
// Phase 1: om[216][64] GEMM (M=224, N=64, K=576); wave w owns M-tiles
//          {2w, 2w+1} (w=3 -> {6}); om -> LDS fp16 quads.
// Phase 2: wave = (pg = px half, kh = K half); lane samples gk=ks*2+(lane>>5)
//          for pixel lane&31; 2 MFMAs per ks; LDS reduce over kh.
// ---------------------------------------------------------------------------
__global__ __launch_bounds__(256) void dcn_fused_kernel(
    const unsigned short* __restrict__ off_f,   // NHWC bf16 [B][H][W][64]
    const unsigned short* __restrict__ gm,      // gmajor bf16 [B][G][H][W][8]
    const unsigned short* __restrict__ wf2,     // om A-frags 32x32
    const float* __restrict__ bom,
    const unsigned short* __restrict__ wdf,     // dcn A-frags 32x32
    const float* __restrict__ bdcn,
    float* __restrict__ out)
{
    __shared__ __half smem_h[64 * OMS];         // 37,376 B (red overlays front)

    const int raw = blockIdx.x;                 // 0..1023
    const int bid = (raw & 7) * 128 + (raw >> 3);   // XCD-contiguous
    const int b = bid >> 8;
    const int rem = bid & 255;
    const int y = rem >> 1;
    const int x0 = (rem & 1) * 64;

    const int tid = threadIdx.x;
    const int lane = tid & 63;
    const int wv = tid >> 6;                    // 0..3
    const int ln32 = lane & 31, hi = lane >> 5;

    // ---------------- Phase 1: om GEMM -------------------------------------
    f32x16 acc1[2][2];
#pragma unroll
    for (int i = 0; i < 2; ++i)
#pragma unroll
        for (int j = 0; j < 2; ++j) acc1[i][j] = (f32x16)(0.f);

    {
        const unsigned short* inb = off_f + (size_t)b * HWSZ * 64;
#pragma unroll 6
        for (int ks = 0; ks < 36; ++ks) {
            const int kb32 = ks >> 1;
            const int c032 = kb32 / 9;
            const int tap = kb32 - c032 * 9;
            const int cin = c032 * 32 + (ks & 1) * 16 + hi * 8;
            const int ky = tap / 3, kx = tap - ky * 3;
            const int yy = y + ky - 1;
            const bool rowv = (unsigned)yy < (unsigned)HH;
            const int yc = rowv ? yy : 0;
            const unsigned short* rowp = inb + (size_t)yc * WWID * 64 + cin;
            bf16x8 bfrag[2];
#pragma unroll
            for (int nt = 0; nt < 2; ++nt) {
                int xx = x0 + nt * 32 + ln32 + kx - 1;
                bool v = rowv && ((unsigned)xx < (unsigned)WWID);
                int xc = v ? xx : 0;
                int4 t = *(const int4*)(rowp + (size_t)xc * 64);
                if (!v) { t.x = 0; t.y = 0; t.z = 0; t.w = 0; }
                bfrag[nt] = *(bf16x8*)&t;
            }
            const bf16x8* af = (const bf16x8*)wf2 + (size_t)ks * 7 * 64 + lane;
#pragma unroll
            for (int i = 0; i < 2; ++i) {
                const int mt = wv * 2 + i;
                if (mt < 7) {
                    bf16x8 a = af[(size_t)mt * 64];
#pragma unroll
                    for (int nt = 0; nt < 2; ++nt)
                        acc1[i][nt] = __builtin_amdgcn_mfma_f32_32x32x16_bf16(
                            a, bfrag[nt], acc1[i][nt], 0, 0, 0);
                }
            }
        }
    }

    // epilogue: om -> LDS fp16 quads (oy,ox,mr,pad) per (pixel, gk)
#pragma unroll
    for (int i = 0; i < 2; ++i) {
        const int mt = wv * 2 + i;
        if (mt >= 7) continue;
#pragma unroll
        for (int nt = 0; nt < 2; ++nt) {
            const int px = nt * 32 + ln32;
#pragma unroll
            for (int r = 0; r < 16; ++r) {
                const int c = mt * 32 + (r & 3) + 8 * (r >> 2) + 4 * hi;
                if (c < C_OM) {
                    const int field = (c >= 144) ? 2 : ((c >= 72) ? 1 : 0);
                    const int gk = c - field * 72;
                    smem_h[px * OMS + gk * 4 + field] =
                        __float2half(acc1[i][nt][r] + bom[c]);
                }
            }
        }
    }
    __syncthreads();

    // ---------------- Phase 2: sampling + einsum ---------------------------
    const int pg = wv & 1, kh = wv >> 1;
    const int pxl = pg * 32 + ln32;    // pixel in block (0..63)
    const int x = x0 + pxl;

    f32x16 acc2[2];
    acc2[0] = (f32x16)(0.f);
    acc2[1] = (f32x16)(0.f);

    const unsigned short* gmb = gm + (size_t)b * 8 * HWSZ * 8;

#pragma unroll 6
    for (int s2 = 0; s2 < 18; ++s2) {
        const int ks = kh * 18 + s2;
        const int gk = ks * 2 + hi;
        const int g = gk / 9;
        const int kt = gk - g * 9;

        const short4 omq = *(const short4*)&smem_h[pxl * OMS + gk * 4];
        const float oy = __half2float(((const __half*)&omq)[0]);
        const float ox = __half2float(((const __half*)&omq)[1]);
        const float mr = __half2float(((const __half*)&omq)[2]);
        const float mv = 1.f / (1.f + __expf(-mr));

        const float pyf = (float)(y + kt / 3 - 1) + oy;
        const float pxf = (float)(x + kt % 3 - 1) + ox;
        const float fy = floorf(pyf), fx = floorf(pxf);
        const float wy = pyf - fy, wx = pxf - fx;
        const int iy = (int)fy, ix = (int)fx;

        float w00 = (1.f - wy) * (1.f - wx);
        float w01 = (1.f - wy) * wx;
        float w10 = wy * (1.f - wx);
        float w11 = wy * wx;

        const bool vy0 = (iy >= 0) && (iy < HH);
        const bool vy1 = (iy + 1 >= 0) && (iy + 1 < HH);
        const bool vx0 = (ix >= 0) && (ix < WWID);
        const bool vx1 = (ix + 1 >= 0) && (ix + 1 < WWID);
        w00 *= (vy0 && vx0) ? mv : 0.f;
        w01 *= (vy0 && vx1) ? mv : 0.f;
        w10 *= (vy1 && vx0) ? mv : 0.f;
        w11 *= (vy1 && vx1) ? mv : 0.f;

        const int y0c = min(max(iy, 0), HH - 1);
        const int y1c = min(max(iy + 1, 0), HH - 1);
        const int x0c = min(max(ix, 0), WWID - 1);
        const int x1c = min(max(ix + 1, 0), WWID - 1);
        const int sel = x1c - x0c;           // 0 or 1

        const float wl0 = w00 + (sel ? 0.f : w01);
        const float wh0 = sel ? w01 : 0.f;
        const float wl1 = w10 + (sel ? 0.f : w11);
        const float wh1 = sel ? w11 : 0.f;

        const unsigned short* pgm = gmb + (size_t)g * HWSZ * 8;
        const size_t rec0 = (size_t)(y0c * WWID + x0c) * 8;
        const size_t rec1 = (size_t)(y1c * WWID + x0c) * 8;
        int4 L0 = *(const int4*)(pgm + rec0);
        int4 H0 = *(const int4*)(pgm + rec0 + 8);
        int4 L1 = *(const int4*)(pgm + rec1);
        int4 H1 = *(const int4*)(pgm + rec1 + 8);
        const unsigned short* l0 = (const unsigned short*)&L0;
        const unsigned short* h0 = (const unsigned short*)&H0;
        const unsigned short* l1 = (const unsigned short*)&L1;
        const unsigned short* h1 = (const unsigned short*)&H1;

        union { bf16x8 v; unsigned short u[8]; } bp;
#pragma unroll
        for (int c = 0; c < 8; ++c) {
            float sv = wl0 * bf2f(l0[c]) + wh0 * bf2f(h0[c])
                     + wl1 * bf2f(l1[c]) + wh1 * bf2f(h1[c]);
            bp.u[c] = f2bf(sv);
        }

        const bf16x8* af = (const bf16x8*)wdf + (size_t)ks * 2 * 64 + lane;
        acc2[0] = __builtin_amdgcn_mfma_f32_32x32x16_bf16(
            af[0], bp.v, acc2[0], 0, 0, 0);
        acc2[1] = __builtin_amdgcn_mfma_f32_32x32x16_bf16(
            af[64], bp.v, acc2[1], 0, 0, 0);
    }

    // ---------------- Reduce over kh + store -------------------------------
    __syncthreads();                    // all om reads done; overlay red
    float* red = (float*)smem_h;        // [2pg][64c][33]
    if (kh == 1) {
#pragma unroll
        for (int mt = 0; mt < 2; ++mt)
#pragma unroll
            for (int r = 0; r < 16; ++r) {
                const int c = mt * 32 + (r & 3) + 8 * (r >> 2) + 4 * hi;
                red[(pg * 64 + c) * 33 + ln32] = acc2[mt][r];
            }
    }
    __syncthreads();
    if (kh == 0) {
#pragma unroll
        for (int mt = 0; mt < 2; ++mt)
#pragma unroll
            for (int r = 0; r < 16; ++r) {
                const int c = mt * 32 + (r & 3) + 8 * (r >> 2) + 4 * hi;
                float v = acc2[mt][r] + red[(pg * 64 + c) * 33 + ln32] + bdcn[c];
                v = (v >= 0.f) ? v : 0.1f * v;
                out[((size_t)(b * NF + c)) * HWSZ + (size_t)y * WWID + x] = v;
            }
    }
}

// ---------------------------------------------------------------------------
extern "C" void kernel_launch(void* const* d_in, const int* in_sizes, int n_in,
                              void* d_out, int out_size, void* d_ws, size_t ws_size,
                              hipStream_t stream)
{
    const float* nbr  = (const float*)d_in[0];
    const float* ref  = (const float*)d_in[1];
    const float* w1   = (const float*)d_in[2];
    const float* b1   = (const float*)d_in[3];
    const float* wom  = (const float*)d_in[4];
    const float* bom  = (const float*)d_in[5];
    const float* wdcn = (const float*)d_in[6];
    const float* bdcn = (const float*)d_in[7];
    float* out = (float*)d_out;

    const size_t NH_B  = (size_t)BB * HWSZ * 128 * 2;     // 16,777,216
    const size_t OFF_B = (size_t)BB * HWSZ * 64 * 2;      //  8,388,608
    const size_t GM_B  = (size_t)BB * HWSZ * 64 * 2 + 64; // + overread pad
    const size_t WF1_B = 36 * 4 * 512 * 2;                //    147,456
    const size_t WF2_B = 36 * 7 * 512 * 2;                //    258,048

    char* ws = (char*)d_ws;
    unsigned short* nhwcin = (unsigned short*)ws;
    unsigned short* off_f  = (unsigned short*)(ws + NH_B);
    unsigned short* gm     = (unsigned short*)(ws + NH_B + OFF_B);
    unsigned short* wf1    = (unsigned short*)(ws + NH_B + OFF_B + GM_B);
    unsigned short* wf2    = wf1 + WF1_B / 2;
    unsigned short* wdf    = wf2 + WF2_B / 2;

    // 1) transpose: concat NHWC128 + group-major gather buffer
    to_nhwc_kernel<<<BB * HH * 2, 256, 0, stream>>>(nbr, ref, nhwcin, gm);

    // 2) all weight repacks (one launch)
    repack_all_kernel<<<936, 256, 0, stream>>>(w1, wom, wdcn, wf1, wf2, wdf);

    // 3) conv1: 128ch -> 64ch + lrelu, NHWC bf16
    conv_mfma_kernel<128, NF, true, 2><<<512, 256, 0, stream>>>(
        nhwcin, wf1, b1, off_f);

    // 4) fused conv_om + deformable conv (64-px blocks, 4 waves, 32x32 MFMA)
    dcn_fused_kernel<<<1024, 256, 0, stream>>>(
        off_f, gm, wf2, bom, wdf, bdcn, out);
}

// Round 8
// 128.449 us; speedup vs baseline: 1.2003x; 1.2003x over previous
//
#include <hip/hip_runtime.h>
#include <hip/hip_bf16.h>
#include <hip/hip_fp16.h>
#include <cmath>

#define NF 64
#define GRP 8
#define CG 8
#define KK 9
#define HH 128
#define WWID 128
#define BB 4
#define HWSZ (HH * WWID)
#define C_OM 216
#define OMS 292   // halfs per pixel in om LDS (8B-aligned quads)

typedef __attribute__((ext_vector_type(8))) short bf16x8;
typedef __attribute__((ext_vector_type(4))) float f32x4;

__device__ inline unsigned short f2bf(float f) {
    union { float f; unsigned u; } x; x.f = f;
    unsigned r = x.u + 0x7fff + ((x.u >> 16) & 1);   // RNE
    return (unsigned short)(r >> 16);
}
__device__ inline float bf2f(unsigned short s) {
    union { unsigned u; float f; } x; x.u = ((unsigned)s) << 16; return x.f;
}

// ---------------------------------------------------------------------------
// NCHW fp32 (nbr ++ ref) -> NHWC bf16 [B][H][W][128]  +  group-major
// gather buffer gm[B][G][H][W][8ch] bf16 (16B records).
// ---------------------------------------------------------------------------
__global__ __launch_bounds__(256) void to_nhwc_kernel(
    const float* __restrict__ nbr, const float* __restrict__ ref,
    unsigned short* __restrict__ out, unsigned short* __restrict__ gm)
{
    __shared__ unsigned short lds[64 * 136];
    const int tid = threadIdx.x, blk = blockIdx.x;
    const int b = blk >> 8, rem = blk & 255, y = rem >> 1, x0 = (rem & 1) * 64;
    const size_t rowoff = (size_t)y * WWID + x0;

    for (int it = 0; it < 32; ++it) {
        int idx = it * 256 + tid;
        int c = idx >> 6, p = idx & 63;
        const float* src = (c < NF) ? (nbr + (size_t)(b * NF + c) * HWSZ)
                                    : (ref + (size_t)(b * NF + c - NF) * HWSZ);
        lds[p * 136 + c] = f2bf(src[rowoff + p]);
    }
    __syncthreads();
    const int p = tid >> 2, c0 = (tid & 3) * 32;
    unsigned short* dst = out + ((size_t)b * HWSZ + rowoff + p) * 128 + c0;
#pragma unroll
    for (int i = 0; i < 8; ++i)
        *(int2*)(dst + i * 4) = *(const int2*)&lds[p * 136 + c0 + i * 4];
    if (c0 < 64) {
#pragma unroll
        for (int gi = 0; gi < 4; ++gi) {
            const int g = (c0 >> 3) + gi;
            *(int4*)(gm + (((size_t)(b * 8 + g)) * HWSZ + rowoff + p) * 8) =
                *(const int4*)&lds[p * 136 + g * 8];
        }
    }
}

// ---------------------------------------------------------------------------
// All weight repacks in one launch (16x16x32 layouts, as in R5).
// wf1: conv1 A-frags (CIN=128, COUT=64, MT=4):   73728
// wf2: om   A-frags (CIN=64, COUT=216, MT=14):  129024
// wdf: dcn  A-frags (K=(g*9+kt)*8+c):            36864
// ---------------------------------------------------------------------------
__global__ void repack_all_kernel(const float* __restrict__ w1,
                                  const float* __restrict__ wom,
                                  const float* __restrict__ wdcn,
                                  unsigned short* __restrict__ wf1,
                                  unsigned short* __restrict__ wf2,
                                  unsigned short* __restrict__ wdf)
{
    int idx = blockIdx.x * 256 + threadIdx.x;
    if (idx < 73728) {
        int j = idx & 7, lane = (idx >> 3) & 63, t = idx >> 9;
        int mt = t % 4, kt = t / 4;
        int c0 = (kt / 9) * 32, tap = kt - (kt / 9) * 9;
        int cout = mt * 16 + (lane & 15);
        int cin = c0 + ((lane >> 4) * 8) + j;
        wf1[idx] = f2bf(w1[((size_t)cout * 128 + cin) * KK + tap]);
        return;
    }
    idx -= 73728;
    if (idx < 129024) {
        int j = idx & 7, lane = (idx >> 3) & 63, t = idx >> 9;
        int mt = t % 14, kt = t / 14;
        int c0 = (kt / 9) * 32, tap = kt - (kt / 9) * 9;
        int cout = mt * 16 + (lane & 15);
        int cin = c0 + ((lane >> 4) * 8) + j;
        float v = (cout < C_OM) ? wom[((size_t)cout * 64 + cin) * KK + tap] : 0.f;
        wf2[idx] = f2bf(v);
        return;
    }
    idx -= 129024;
    if (idx < 36864) {
        int j = idx & 7, lane = (idx >> 3) & 63, t = idx >> 9;
        int mt = t & 3, s = t >> 2;
        int cout = mt * 16 + (lane & 15);
        int kglob = s * 32 + (lane >> 4) * 8 + j;
        int gk = kglob >> 3, c = kglob & 7;
        int g = gk / 9, kt = gk - g * 9;
        wdf[idx] = f2bf(wdcn[((size_t)cout * NF + g * 8 + c) * 9 + kt]);
    }
}

// ---------------------------------------------------------------------------
// Implicit-GEMM 3x3 conv (conv1) via mfma_f32_16x16x32_bf16.
// ---------------------------------------------------------------------------
template <int CIN, int COUT, bool LRELU, int NT>
__global__ __launch_bounds__(256) void conv_mfma_kernel(
    const unsigned short* __restrict__ in,
    const unsigned short* __restrict__ wf,
    const float* __restrict__ bias,
    unsigned short* __restrict__ dst)
{
    const int tid = threadIdx.x;
    const int lane = tid & 63;
    const int wv = tid >> 6;
    const int ng = blockIdx.x * 4 + wv;
    constexpr int SEG = 128 / (16 * NT);
    const int x0 = (ng % SEG) * (16 * NT);
    const int y  = (ng / SEG) % 128;
    const int b  = ng / (SEG * 128);
    const int ln = lane & 15, kb = lane >> 4;

    f32x4 acc[4][NT];
#pragma unroll
    for (int i = 0; i < 4; ++i)
#pragma unroll
        for (int j = 0; j < NT; ++j) acc[i][j] = f32x4{0.f, 0.f, 0.f, 0.f};

    const unsigned short* inb = in + (size_t)b * HWSZ * CIN + (size_t)kb * 8;

    for (int c0 = 0; c0 < CIN; c0 += 32) {
#pragma unroll
        for (int tap = 0; tap < 9; ++tap) {
            const int ky = tap / 3, kx = tap % 3;
            const int yy = y + ky - 1;
            const bool rowv = (unsigned)yy < (unsigned)HH;
            const int yc = rowv ? yy : 0;
            const unsigned short* rowp = inb + (size_t)yc * WWID * CIN + c0;
            bf16x8 bfrag[NT];
#pragma unroll
            for (int nt = 0; nt < NT; ++nt) {
                int xx = x0 + nt * 16 + ln + kx - 1;
                bool v = rowv && ((unsigned)xx < (unsigned)WWID);
                int xc = v ? xx : 0;
                int4 t = *(const int4*)(rowp + (size_t)xc * CIN);
                if (!v) { t.x = 0; t.y = 0; t.z = 0; t.w = 0; }
                bfrag[nt] = *(bf16x8*)&t;
            }
            const int kt = (c0 / 32) * 9 + tap;
            const bf16x8* af = (const bf16x8*)wf + (size_t)kt * 4 * 64 + lane;
            bf16x8 afrag[4];
#pragma unroll
            for (int mt = 0; mt < 4; ++mt) afrag[mt] = af[(size_t)mt * 64];
#pragma unroll
            for (int mt = 0; mt < 4; ++mt)
#pragma unroll
                for (int nt = 0; nt < NT; ++nt)
                    acc[mt][nt] = __builtin_amdgcn_mfma_f32_16x16x32_bf16(
                        afrag[mt], bfrag[nt], acc[mt][nt], 0, 0, 0);
        }
    }

#pragma unroll
    for (int mt = 0; mt < 4; ++mt) {
        const int cout = mt * 16 + kb * 4;
        const float b0 = bias[cout], b1 = bias[cout + 1];
        const float b2 = bias[cout + 2], b3 = bias[cout + 3];
#pragma unroll
        for (int nt = 0; nt < NT; ++nt) {
            const int px = x0 + nt * 16 + ln;
            const size_t pix = (size_t)b * HWSZ + (size_t)y * WWID + px;
            f32x4 v = acc[mt][nt];
            v[0] += b0; v[1] += b1; v[2] += b2; v[3] += b3;
            if (LRELU) {
#pragma unroll
                for (int r = 0; r < 4; ++r) v[r] = (v[r] >= 0.f) ? v[r] : 0.1f * v[r];
            }
            int2 pk;
            pk.x = (int)f2bf(v[0]) | ((int)f2bf(v[1]) << 16);
            pk.y = (int)f2bf(v[2]) | ((int)f2bf(v[3]) << 16);
            *(int2*)(dst + pix * COUT + cout) = pk;
        }
    }
}

// ---------------------------------------------------------------------------
// FUSED conv_om + DCN (R5 structure + chain-shortening).
// Block = 128 threads (2 waves), 32 pixels, grid 2048.
// Phase 1:   om[216][32] implicit-GEMM -> LDS fp16 (oy,ox,mr,pad) quads.
// Phase 1.5: in-place sigmoid of the mr field (removes exp from phase 2).
// Phase 2:   wave = 16 px x full K, 3 chunks x 6 steps with chunk-level
//            om-quad register prefetch; gathers from group-major 16B recs.
// ---------------------------------------------------------------------------
__global__ __launch_bounds__(128, 4) void dcn_fused_kernel(
    const unsigned short* __restrict__ off_f,   // NHWC bf16 [B][H][W][64]
    const unsigned short* __restrict__ gm,      // gmajor bf16 [B][G][H][W][8]
    const unsigned short* __restrict__ wf2,     // om A-frags (MT=14)
    const float* __restrict__ bom,
    const unsigned short* __restrict__ wdf,     // dcn A-frags
    const float* __restrict__ bdcn,
    float* __restrict__ out)
{
    __shared__ __half smem_h[32 * OMS];         // 18,688 B

    const int raw = blockIdx.x;                 // 0..2047
    const int bid = (raw & 7) * 256 + (raw >> 3);   // XCD-contiguous
    const int b = bid >> 9;
    const int rem = bid & 511;
    const int y = rem >> 2;
    const int x0 = (rem & 3) * 32;

    const int tid = threadIdx.x;
    const int lane = tid & 63;
    const int wv = tid >> 6;                    // 0..1
    const int ln = lane & 15, kb = lane >> 4;

    // ---------------- Phase 1: om GEMM (M=224 pad, N=32, K=576) -----------
    f32x4 acc1[7][2];
#pragma unroll
    for (int i = 0; i < 7; ++i)
#pragma unroll
        for (int j = 0; j < 2; ++j) acc1[i][j] = f32x4{0.f, 0.f, 0.f, 0.f};

    {
        const unsigned short* inb = off_f + (size_t)b * HWSZ * 64 + (size_t)kb * 8;
        for (int c0 = 0; c0 < 64; c0 += 32) {
#pragma unroll
            for (int tap = 0; tap < 9; ++tap) {
                const int ky = tap / 3, kx = tap % 3;
                const int yy = y + ky - 1;
                const bool rowv = (unsigned)yy < (unsigned)HH;
                const int yc = rowv ? yy : 0;
                const unsigned short* rowp = inb + (size_t)yc * WWID * 64 + c0;
                bf16x8 bfrag[2];
#pragma unroll
                for (int nt = 0; nt < 2; ++nt) {
                    int xx = x0 + nt * 16 + ln + kx - 1;
                    bool v = rowv && ((unsigned)xx < (unsigned)WWID);
                    int xc = v ? xx : 0;
                    int4 t = *(const int4*)(rowp + (size_t)xc * 64);
                    if (!v) { t.x = 0; t.y = 0; t.z = 0; t.w = 0; }
                    bfrag[nt] = *(bf16x8*)&t;
                }
                const int kt = (c0 / 32) * 9 + tap;
                const bf16x8* af = (const bf16x8*)wf2 + (size_t)kt * 14 * 64 + lane;
#pragma unroll
                for (int i = 0; i < 7; ++i) {
                    const int mt = wv * 7 + i;
                    bf16x8 a = af[(size_t)mt * 64];
#pragma unroll
                    for (int nt = 0; nt < 2; ++nt)
                        acc1[i][nt] = __builtin_amdgcn_mfma_f32_16x16x32_bf16(
                            a, bfrag[nt], acc1[i][nt], 0, 0, 0);
                }
            }
        }
    }

    // epilogue: om -> LDS fp16 quads (oy,ox,mr,pad) per (pixel, gk)
#pragma unroll
    for (int i = 0; i < 7; ++i) {
        const int mt = wv * 7 + i;
        const int cb = mt * 16 + kb * 4;
#pragma unroll
        for (int nt = 0; nt < 2; ++nt) {
            const int px = nt * 16 + ln;
#pragma unroll
            for (int r = 0; r < 4; ++r) {
                const int c = cb + r;
                if (c < C_OM) {
                    const int field = (c >= 144) ? 2 : ((c >= 72) ? 1 : 0);
                    const int gk = c - field * 72;
                    smem_h[px * OMS + gk * 4 + field] =
                        __float2half(acc1[i][nt][r] + bom[c]);
                }
            }
        }
    }
    __syncthreads();

    // ---------------- Phase 1.5: in-place sigmoid of mr --------------------
    {
        const int px = tid & 31;
        const int g0 = (tid >> 5) * 18;          // 4 slices of 18 gk
        __half* base = &smem_h[px * OMS];
#pragma unroll
        for (int i = 0; i < 18; ++i) {
            const int gk = g0 + i;
            const float mr = __half2float(base[gk * 4 + 2]);
            base[gk * 4 + 2] = __float2half(1.f / (1.f + __expf(-mr)));
        }
    }
    __syncthreads();

    // ---------------- Phase 2: sampling + einsum (full K per wave) ---------
    const int pxl = wv * 16 + ln;      // 0..31
    const int x = x0 + pxl;

    f32x4 acc[4];
#pragma unroll
    for (int mt = 0; mt < 4; ++mt) acc[mt] = f32x4{0.f, 0.f, 0.f, 0.f};

    const unsigned short* gmb = gm + (size_t)b * 8 * HWSZ * 8;

#pragma unroll
    for (int ch = 0; ch < 3; ++ch) {
        // chunk prefetch: 6 om quads into registers (independent ds_reads)
        short4 q[6];
#pragma unroll
        for (int i = 0; i < 6; ++i) {
            const int gk = (ch * 6 + i) * 4 + kb;
            q[i] = *(const short4*)&smem_h[pxl * OMS + gk * 4];
        }

#pragma unroll
        for (int i = 0; i < 6; ++i) {
            const int s = ch * 6 + i;
            const int gk = s * 4 + kb;
            const int g = gk / 9;
            const int kt = gk - g * 9;

            const float oy = __half2float(((const __half*)&q[i])[0]);
            const float ox = __half2float(((const __half*)&q[i])[1]);
            const float mv = __half2float(((const __half*)&q[i])[2]);  // pre-sigmoided

            const float pyf = (float)(y + kt / 3 - 1) + oy;
            const float pxf = (float)(x + kt % 3 - 1) + ox;
            const float fy = floorf(pyf), fx = floorf(pxf);
            const float wy = pyf - fy, wx = pxf - fx;
            const int iy = (int)fy, ix = (int)fx;

            float w00 = (1.f - wy) * (1.f - wx);
            float w01 = (1.f - wy) * wx;
            float w10 = wy * (1.f - wx);
            float w11 = wy * wx;

            const bool vy0 = (iy >= 0) && (iy < HH);
            const bool vy1 = (iy + 1 >= 0) && (iy + 1 < HH);
            const bool vx0 = (ix >= 0) && (ix < WWID);
            const bool vx1 = (ix + 1 >= 0) && (ix + 1 < WWID);
            w00 *= (vy0 && vx0) ? mv : 0.f;
            w01 *= (vy0 && vx1) ? mv : 0.f;
            w10 *= (vy1 && vx0) ? mv : 0.f;
            w11 *= (vy1 && vx1) ? mv : 0.f;

            const int y0c = min(max(iy, 0), HH - 1);
            const int y1c = min(max(iy + 1, 0), HH - 1);
            const int x0c = min(max(ix, 0), WWID - 1);
            const int x1c = min(max(ix + 1, 0), WWID - 1);
            const int sel = x1c - x0c;           // 0 or 1

            // fold x-corner selection into weights
            const float wl0 = w00 + (sel ? 0.f : w01);
            const float wh0 = sel ? w01 : 0.f;
            const float wl1 = w10 + (sel ? 0.f : w11);
            const float wh1 = sel ? w11 : 0.f;

            const unsigned short* pgm = gmb + (size_t)g * HWSZ * 8;
            const size_t rec0 = (size_t)(y0c * WWID + x0c) * 8;
            const size_t rec1 = (size_t)(y1c * WWID + x0c) * 8;
            int4 L0 = *(const int4*)(pgm + rec0);
            int4 H0 = *(const int4*)(pgm + rec0 + 8);
            int4 L1 = *(const int4*)(pgm + rec1);
            int4 H1 = *(const int4*)(pgm + rec1 + 8);
            const unsigned short* l0 = (const unsigned short*)&L0;
            const unsigned short* h0 = (const unsigned short*)&H0;
            const unsigned short* l1 = (const unsigned short*)&L1;
            const unsigned short* h1 = (const unsigned short*)&H1;

            union { bf16x8 v; unsigned short u[8]; } bp;
#pragma unroll
            for (int c = 0; c < 8; ++c) {
                float sv = wl0 * bf2f(l0[c]) + wh0 * bf2f(h0[c])
                         + wl1 * bf2f(l1[c]) + wh1 * bf2f(h1[c]);
                bp.u[c] = f2bf(sv);
            }

            const bf16x8* af = (const bf16x8*)wdf + ((size_t)s * 4) * 64 + lane;
#pragma unroll
            for (int mt = 0; mt < 4; ++mt)
                acc[mt] = __builtin_amdgcn_mfma_f32_16x16x32_bf16(
                    af[(size_t)mt * 64], bp.v, acc[mt], 0, 0, 0);
        }
    }

    // ---------------- Epilogue: direct store -------------------------------
#pragma unroll
    for (int mt = 0; mt < 4; ++mt) {
#pragma unroll
        for (int r = 0; r < 4; ++r) {
            const int cout = mt * 16 + kb * 4 + r;
            float v = acc[mt][r] + bdcn[cout];
            v = (v >= 0.f) ? v : 0.1f * v;
            out[((size_t)(b * NF + cout)) * HWSZ + (size_t)y * WWID + x] = v;
        }
    }
}

// ---------------------------------------------------------------------------
extern "C" void kernel_launch(void* const* d_in, const int* in_sizes, int n_in,
                              void* d_out, int out_size, void* d_ws, size_t ws_size,
                              hipStream_t stream)
{
    const float* nbr  = (const float*)d_in[0];
    const float* ref  = (const float*)d_in[1];
    const float* w1   = (const float*)d_in[2];
    const float* b1   = (const float*)d_in[3];
    const float* wom  = (const float*)d_in[4];
    const float* bom  = (const float*)d_in[5];
    const float* wdcn = (const float*)d_in[6];
    const float* bdcn = (const float*)d_in[7];
    float* out = (float*)d_out;

    const size_t NH_B  = (size_t)BB * HWSZ * 128 * 2;     // 16,777,216
    const size_t OFF_B = (size_t)BB * HWSZ * 64 * 2;      //  8,388,608
    const size_t GM_B  = (size_t)BB * HWSZ * 64 * 2 + 64; // + overread pad
    const size_t WF1_B = 36 * 4 * 512 * 2;                //    147,456
    const size_t WF2_B = 18 * 14 * 512 * 2;               //    258,048

    char* ws = (char*)d_ws;
    unsigned short* nhwcin = (unsigned short*)ws;
    unsigned short* off_f  = (unsigned short*)(ws + NH_B);
    unsigned short* gm     = (unsigned short*)(ws + NH_B + OFF_B);
    unsigned short* wf1    = (unsigned short*)(ws + NH_B + OFF_B + GM_B);
    unsigned short* wf2    = wf1 + WF1_B / 2;
    unsigned short* wdf    = wf2 + WF2_B / 2;

    // 1) transpose: concat NHWC128 + group-major gather buffer
    to_nhwc_kernel<<<BB * HH * 2, 256, 0, stream>>>(nbr, ref, nhwcin, gm);

    // 2) all weight repacks (one launch)
    repack_all_kernel<<<936, 256, 0, stream>>>(w1, wom, wdcn, wf1, wf2, wdf);

    // 3) conv1: 128ch -> 64ch + lrelu, NHWC bf16
    conv_mfma_kernel<128, NF, true, 2><<<512, 256, 0, stream>>>(
        nhwcin, wf1, b1, off_f);

    // 4) fused conv_om + deformable conv (32-px blocks, 2 waves, full-K)
    dcn_fused_kernel<<<2048, 128, 0, stream>>>(
        off_f, gm, wf2, bom, wdf, bdcn, out);
}

// Round 9
// 124.503 us; speedup vs baseline: 1.2383x; 1.0317x over previous
//
#include <hip/hip_runtime.h>
#include <hip/hip_bf16.h>
#include <hip/hip_fp16.h>
#include <cmath>

#define NF 64
#define GRP 8
#define CG 8
#define KK 9
#define HH 128
#define WWID 128
#define BB 4
#define HWSZ (HH * WWID)
#define C_OM 216
#define OMS 292   // halfs per pixel in om LDS (8B-aligned quads)

typedef __attribute__((ext_vector_type(8))) short bf16x8;
typedef __attribute__((ext_vector_type(8))) _Float16 f16x8;
typedef __attribute__((ext_vector_type(4))) float f32x4;

__device__ inline unsigned short f2bf(float f) {
    union { float f; unsigned u; } x; x.f = f;
    unsigned r = x.u + 0x7fff + ((x.u >> 16) & 1);   // RNE
    return (unsigned short)(r >> 16);
}
__device__ inline float bf2f(unsigned short s) {
    union { unsigned u; float f; } x; x.u = ((unsigned)s) << 16; return x.f;
}

// ---------------------------------------------------------------------------
// PREP kernel: blocks 0..1023  = NCHW fp32 (nbr ++ ref) -> NHWC bf16
//              [B][H][W][128] + group-major FP16 gather buffer
//              gm[B][G][H][W][8ch] (16B records).
//              blocks 1024+    = all weight repacks.
// wf1: conv1 A-frags bf16 (CIN=128, COUT=64, MT=4):   73728
// wf2: om   A-frags bf16 (CIN=64, COUT=216, MT=14):  129024
// wdf: dcn  A-frags FP16 (K=(g*9+kt)*8+c):            36864
// ---------------------------------------------------------------------------
__global__ __launch_bounds__(256) void prep_kernel(
    const float* __restrict__ nbr, const float* __restrict__ ref,
    const float* __restrict__ w1, const float* __restrict__ wom,
    const float* __restrict__ wdcn,
    unsigned short* __restrict__ out, unsigned short* __restrict__ gm,
    unsigned short* __restrict__ wf1, unsigned short* __restrict__ wf2,
    unsigned short* __restrict__ wdf)
{
    __shared__ unsigned short lds[64 * 136];
    __shared__ __half lds_h[64 * 72];
    const int tid = threadIdx.x;

    if (blockIdx.x < 1024) {
        const int blk = blockIdx.x;
        const int b = blk >> 8, rem = blk & 255, y = rem >> 1, x0 = (rem & 1) * 64;
        const size_t rowoff = (size_t)y * WWID + x0;

        for (int it = 0; it < 32; ++it) {
            int idx = it * 256 + tid;
            int c = idx >> 6, p = idx & 63;
            const float* src = (c < NF) ? (nbr + (size_t)(b * NF + c) * HWSZ)
                                        : (ref + (size_t)(b * NF + c - NF) * HWSZ);
            const float v = src[rowoff + p];
            lds[p * 136 + c] = f2bf(v);
            if (c < 64) lds_h[p * 72 + c] = __float2half(v);
        }
        __syncthreads();
        const int p = tid >> 2, c0 = (tid & 3) * 32;
        unsigned short* dst = out + ((size_t)b * HWSZ + rowoff + p) * 128 + c0;
#pragma unroll
        for (int i = 0; i < 8; ++i)
            *(int2*)(dst + i * 4) = *(const int2*)&lds[p * 136 + c0 + i * 4];
        if (c0 < 64) {
#pragma unroll
            for (int gi = 0; gi < 4; ++gi) {
                const int g = (c0 >> 3) + gi;
                *(int4*)(gm + (((size_t)(b * 8 + g)) * HWSZ + rowoff + p) * 8) =
                    *(const int4*)&lds_h[p * 72 + g * 8];
            }
        }
        return;
    }

    int idx = (blockIdx.x - 1024) * 256 + tid;
    if (idx < 73728) {
        int j = idx & 7, lane = (idx >> 3) & 63, t = idx >> 9;
        int mt = t % 4, kt = t / 4;
        int c0 = (kt / 9) * 32, tap = kt - (kt / 9) * 9;
        int cout = mt * 16 + (lane & 15);
        int cin = c0 + ((lane >> 4) * 8) + j;
        wf1[idx] = f2bf(w1[((size_t)cout * 128 + cin) * KK + tap]);
        return;
    }
    idx -= 73728;
    if (idx < 129024) {
        int j = idx & 7, lane = (idx >> 3) & 63, t = idx >> 9;
        int mt = t % 14, kt = t / 14;
        int c0 = (kt / 9) * 32, tap = kt - (kt / 9) * 9;
        int cout = mt * 16 + (lane & 15);
        int cin = c0 + ((lane >> 4) * 8) + j;
        float v = (cout < C_OM) ? wom[((size_t)cout * 64 + cin) * KK + tap] : 0.f;
        wf2[idx] = f2bf(v);
        return;
    }
    idx -= 129024;
    if (idx < 36864) {
        int j = idx & 7, lane = (idx >> 3) & 63, t = idx >> 9;
        int mt = t & 3, s = t >> 2;
        int cout = mt * 16 + (lane & 15);
        int kglob = s * 32 + (lane >> 4) * 8 + j;
        int gk = kglob >> 3, c = kglob & 7;
        int g = gk / 9, kt = gk - g * 9;
        const __half hv = __float2half(wdcn[((size_t)cout * NF + g * 8 + c) * 9 + kt]);
        wdf[idx] = *(const unsigned short*)&hv;
    }
}

// ---------------------------------------------------------------------------
// Implicit-GEMM 3x3 conv (conv1) via mfma_f32_16x16x32_bf16.
// ---------------------------------------------------------------------------
template <int CIN, int COUT, bool LRELU, int NT>
__global__ __launch_bounds__(256) void conv_mfma_kernel(
    const unsigned short* __restrict__ in,
    const unsigned short* __restrict__ wf,
    const float* __restrict__ bias,
    unsigned short* __restrict__ dst)
{
    const int tid = threadIdx.x;
    const int lane = tid & 63;
    const int wv = tid >> 6;
    const int ng = blockIdx.x * 4 + wv;
    constexpr int SEG = 128 / (16 * NT);
    const int x0 = (ng % SEG) * (16 * NT);
    const int y  = (ng / SEG) % 128;
    const int b  = ng / (SEG * 128);
    const int ln = lane & 15, kb = lane >> 4;

    f32x4 acc[4][NT];
#pragma unroll
    for (int i = 0; i < 4; ++i)
#pragma unroll
        for (int j = 0; j < NT; ++j) acc[i][j] = f32x4{0.f, 0.f, 0.f, 0.f};

    const unsigned short* inb = in + (size_t)b * HWSZ * CIN + (size_t)kb * 8;

    for (int c0 = 0; c0 < CIN; c0 += 32) {
#pragma unroll
        for (int tap = 0; tap < 9; ++tap) {
            const int ky = tap / 3, kx = tap % 3;
            const int yy = y + ky - 1;
            const bool rowv = (unsigned)yy < (unsigned)HH;
            const int yc = rowv ? yy : 0;
            const unsigned short* rowp = inb + (size_t)yc * WWID * CIN + c0;
            bf16x8 bfrag[NT];
#pragma unroll
            for (int nt = 0; nt < NT; ++nt) {
                int xx = x0 + nt * 16 + ln + kx - 1;
                bool v = rowv && ((unsigned)xx < (unsigned)WWID);
                int xc = v ? xx : 0;
                int4 t = *(const int4*)(rowp + (size_t)xc * CIN);
                if (!v) { t.x = 0; t.y = 0; t.z = 0; t.w = 0; }
                bfrag[nt] = *(bf16x8*)&t;
            }
            const int kt = (c0 / 32) * 9 + tap;
            const bf16x8* af = (const bf16x8*)wf + (size_t)kt * 4 * 64 + lane;
            bf16x8 afrag[4];
#pragma unroll
            for (int mt = 0; mt < 4; ++mt) afrag[mt] = af[(size_t)mt * 64];
#pragma unroll
            for (int mt = 0; mt < 4; ++mt)
#pragma unroll
                for (int nt = 0; nt < NT; ++nt)
                    acc[mt][nt] = __builtin_amdgcn_mfma_f32_16x16x32_bf16(
                        afrag[mt], bfrag[nt], acc[mt][nt], 0, 0, 0);
        }
    }

#pragma unroll
    for (int mt = 0; mt < 4; ++mt) {
        const int cout = mt * 16 + kb * 4;
        const float b0 = bias[cout], b1 = bias[cout + 1];
        const float b2 = bias[cout + 2], b3 = bias[cout + 3];
#pragma unroll
        for (int nt = 0; nt < NT; ++nt) {
            const int px = x0 + nt * 16 + ln;
            const size_t pix = (size_t)b * HWSZ + (size_t)y * WWID + px;
            f32x4 v = acc[mt][nt];
            v[0] += b0; v[1] += b1; v[2] += b2; v[3] += b3;
            if (LRELU) {
#pragma unroll
                for (int r = 0; r < 4; ++r) v[r] = (v[r] >= 0.f) ? v[r] : 0.1f * v[r];
            }
            int2 pk;
            pk.x = (int)f2bf(v[0]) | ((int)f2bf(v[1]) << 16);
            pk.y = (int)f2bf(v[2]) | ((int)f2bf(v[3]) << 16);
            *(int2*)(dst + pix * COUT + cout) = pk;
        }
    }
}

// ---------------------------------------------------------------------------
// FUSED conv_om + DCN. Block = 128 threads (2 waves), 32 pixels, grid 2048.
// Phase 1:   om[216][32] implicit-GEMM (bf16) -> LDS fp16 quads.
// Phase 1.5: in-place sigmoid of mr.
// Phase 2:   full K per wave; FP16 gather records; packed v_pk_fma_f16
//            interpolation straight from loaded registers; f16 MFMA.
// ---------------------------------------------------------------------------
__global__ __launch_bounds__(128, 4) void dcn_fused_kernel(
    const unsigned short* __restrict__ off_f,   // NHWC bf16 [B][H][W][64]
    const unsigned short* __restrict__ gm,      // gmajor FP16 [B][G][H][W][8]
    const unsigned short* __restrict__ wf2,     // om A-frags bf16 (MT=14)
    const float* __restrict__ bom,
    const unsigned short* __restrict__ wdf,     // dcn A-frags FP16
    const float* __restrict__ bdcn,
    float* __restrict__ out)
{
    __shared__ __half smem_h[32 * OMS];         // 18,688 B

    const int raw = blockIdx.x;                 // 0..2047
    const int bid = (raw & 7) * 256 + (raw >> 3);   // XCD-contiguous
    const int b = bid >> 9;
    const int rem = bid & 511;
    const int y = rem >> 2;
    const int x0 = (rem & 3) * 32;

    const int tid = threadIdx.x;
    const int lane = tid & 63;
    const int wv = tid >> 6;                    // 0..1
    const int ln = lane & 15, kb = lane >> 4;

    // ---------------- Phase 1: om GEMM (M=224 pad, N=32, K=576) -----------
    f32x4 acc1[7][2];
#pragma unroll
    for (int i = 0; i < 7; ++i)
#pragma unroll
        for (int j = 0; j < 2; ++j) acc1[i][j] = f32x4{0.f, 0.f, 0.f, 0.f};

    {
        const unsigned short* inb = off_f + (size_t)b * HWSZ * 64 + (size_t)kb * 8;
        for (int c0 = 0; c0 < 64; c0 += 32) {
#pragma unroll
            for (int tap = 0; tap < 9; ++tap) {
                const int ky = tap / 3, kx = tap % 3;
                const int yy = y + ky - 1;
                const bool rowv = (unsigned)yy < (unsigned)HH;
                const int yc = rowv ? yy : 0;
                const unsigned short* rowp = inb + (size_t)yc * WWID * 64 + c0;
                bf16x8 bfrag[2];
#pragma unroll
                for (int nt = 0; nt < 2; ++nt) {
                    int xx = x0 + nt * 16 + ln + kx - 1;
                    bool v = rowv && ((unsigned)xx < (unsigned)WWID);
                    int xc = v ? xx : 0;
                    int4 t = *(const int4*)(rowp + (size_t)xc * 64);
                    if (!v) { t.x = 0; t.y = 0; t.z = 0; t.w = 0; }
                    bfrag[nt] = *(bf16x8*)&t;
                }
                const int kt = (c0 / 32) * 9 + tap;
                const bf16x8* af = (const bf16x8*)wf2 + (size_t)kt * 14 * 64 + lane;
#pragma unroll
                for (int i = 0; i < 7; ++i) {
                    const int mt = wv * 7 + i;
                    bf16x8 a = af[(size_t)mt * 64];
#pragma unroll
                    for (int nt = 0; nt < 2; ++nt)
                        acc1[i][nt] = __builtin_amdgcn_mfma_f32_16x16x32_bf16(
                            a, bfrag[nt], acc1[i][nt], 0, 0, 0);
                }
            }
        }
    }

    // epilogue: om -> LDS fp16 quads (oy,ox,mr,pad) per (pixel, gk)
#pragma unroll
    for (int i = 0; i < 7; ++i) {
        const int mt = wv * 7 + i;
        const int cb = mt * 16 + kb * 4;
#pragma unroll
        for (int nt = 0; nt < 2; ++nt) {
            const int px = nt * 16 + ln;
#pragma unroll
            for (int r = 0; r < 4; ++r) {
                const int c = cb + r;
                if (c < C_OM) {
                    const int field = (c >= 144) ? 2 : ((c >= 72) ? 1 : 0);
                    const int gk = c - field * 72;
                    smem_h[px * OMS + gk * 4 + field] =
                        __float2half(acc1[i][nt][r] + bom[c]);
                }
            }
        }
    }
    __syncthreads();

    // ---------------- Phase 1.5: in-place sigmoid of mr --------------------
    {
        const int px = tid & 31;
        const int g0 = (tid >> 5) * 18;          // 4 slices of 18 gk
        __half* base = &smem_h[px * OMS];
#pragma unroll
        for (int i = 0; i < 18; ++i) {
            const int gk = g0 + i;
            const float mr = __half2float(base[gk * 4 + 2]);
            base[gk * 4 + 2] = __float2half(1.f / (1.f + __expf(-mr)));
        }
    }
    __syncthreads();

    // ---------------- Phase 2: sampling + einsum (full K per wave) ---------
    const int pxl = wv * 16 + ln;      // 0..31
    const int x = x0 + pxl;

    f32x4 acc[4];
#pragma unroll
    for (int mt = 0; mt < 4; ++mt) acc[mt] = f32x4{0.f, 0.f, 0.f, 0.f};

    const unsigned short* gmb = gm + (size_t)b * 8 * HWSZ * 8;

#pragma unroll
    for (int ch = 0; ch < 3; ++ch) {
        // chunk prefetch: 6 om quads into registers (independent ds_reads)
        short4 q[6];
#pragma unroll
        for (int i = 0; i < 6; ++i) {
            const int gk = (ch * 6 + i) * 4 + kb;
            q[i] = *(const short4*)&smem_h[pxl * OMS + gk * 4];
        }

#pragma unroll
        for (int i = 0; i < 6; ++i) {
            const int s = ch * 6 + i;
            const int gk = s * 4 + kb;
            const int g = gk / 9;
            const int kt = gk - g * 9;

            const float oy = __half2float(((const __half*)&q[i])[0]);
            const float ox = __half2float(((const __half*)&q[i])[1]);
            const float mv = __half2float(((const __half*)&q[i])[2]);  // pre-sigmoided

            const float pyf = (float)(y + kt / 3 - 1) + oy;
            const float pxf = (float)(x + kt % 3 - 1) + ox;
            const float fy = floorf(pyf), fx = floorf(pxf);
            const float wy = pyf - fy, wx = pxf - fx;
            const int iy = (int)fy, ix = (int)fx;

            float w00 = (1.f - wy) * (1.f - wx);
            float w01 = (1.f - wy) * wx;
            float w10 = wy * (1.f - wx);
            float w11 = wy * wx;

            const bool vy0 = (iy >= 0) && (iy < HH);
            const bool vy1 = (iy + 1 >= 0) && (iy + 1 < HH);
            const bool vx0 = (ix >= 0) && (ix < WWID);
            const bool vx1 = (ix + 1 >= 0) && (ix + 1 < WWID);
            w00 *= (vy0 && vx0) ? mv : 0.f;
            w01 *= (vy0 && vx1) ? mv : 0.f;
            w10 *= (vy1 && vx0) ? mv : 0.f;
            w11 *= (vy1 && vx1) ? mv : 0.f;

            const int y0c = min(max(iy, 0), HH - 1);
            const int y1c = min(max(iy + 1, 0), HH - 1);
            const int x0c = min(max(ix, 0), WWID - 1);
            const int x1c = min(max(ix + 1, 0), WWID - 1);
            const int sel = x1c - x0c;           // 0 or 1

            // fold x-corner selection into weights
            const float wl0 = w00 + (sel ? 0.f : w01);
            const float wh0 = sel ? w01 : 0.f;
            const float wl1 = w10 + (sel ? 0.f : w11);
            const float wh1 = sel ? w11 : 0.f;

            const unsigned short* pgm = gmb + (size_t)g * HWSZ * 8;
            const size_t rec0 = (size_t)(y0c * WWID + x0c) * 8;
            const size_t rec1 = (size_t)(y1c * WWID + x0c) * 8;
            int4 L0 = *(const int4*)(pgm + rec0);
            int4 H0 = *(const int4*)(pgm + rec0 + 8);
            int4 L1 = *(const int4*)(pgm + rec1);
            int4 H1 = *(const int4*)(pgm + rec1 + 8);

            // packed fp16 interpolation: no unpack/repack, 2 ch per inst
            const __half2 wl0h = __float2half2_rn(wl0);
            const __half2 wh0h = __float2half2_rn(wh0);
            const __half2 wl1h = __float2half2_rn(wl1);
            const __half2 wh1h = __float2half2_rn(wh1);
            const __half2* l0 = (const __half2*)&L0;
            const __half2* h0 = (const __half2*)&H0;
            const __half2* l1 = (const __half2*)&L1;
            const __half2* h1 = (const __half2*)&H1;
            __half2 bp0 = __hfma2(l0[0], wl0h, __hfma2(h0[0], wh0h,
                          __hfma2(l1[0], wl1h, __hmul2(h1[0], wh1h))));
            __half2 bp1 = __hfma2(l0[1], wl0h, __hfma2(h0[1], wh0h,
                          __hfma2(l1[1], wl1h, __hmul2(h1[1], wh1h))));
            __half2 bp2 = __hfma2(l0[2], wl0h, __hfma2(h0[2], wh0h,
                          __hfma2(l1[2], wl1h, __hmul2(h1[2], wh1h))));
            __half2 bp3 = __hfma2(l0[3], wl0h, __hfma2(h0[3], wh0h,
                          __hfma2(l1[3], wl1h, __hmul2(h1[3], wh1h))));
            __half2 bpv[4] = {bp0, bp1, bp2, bp3};
            const f16x8 bfrag = *(const f16x8*)bpv;

            const f16x8* af = (const f16x8*)wdf + ((size_t)s * 4) * 64 + lane;
#pragma unroll
            for (int mt = 0; mt < 4; ++mt)
                acc[mt] = __builtin_amdgcn_mfma_f32_16x16x32_f16(
                    af[(size_t)mt * 64], bfrag, acc[mt], 0, 0, 0);
        }
    }

    // ---------------- Epilogue: direct store -------------------------------
#pragma unroll
    for (int mt = 0; mt < 4; ++mt) {
#pragma unroll
        for (int r = 0; r < 4; ++r) {
            const int cout = mt * 16 + kb * 4 + r;
            float v = acc[mt][r] + bdcn[cout];
            v = (v >= 0.f) ? v : 0.1f * v;
            out[((size_t)(b * NF + cout)) * HWSZ + (size_t)y * WWID + x] = v;
        }
    }
}

// ---------------------------------------------------------------------------
extern "C" void kernel_launch(void* const* d_in, const int* in_sizes, int n_in,
                              void* d_out, int out_size, void* d_ws, size_t ws_size,
                              hipStream_t stream)
{
    const float* nbr  = (const float*)d_in[0];
    const float* ref  = (const float*)d_in[1];
    const float* w1   = (const float*)d_in[2];
    const float* b1   = (const float*)d_in[3];
    const float* wom  = (const float*)d_in[4];
    const float* bom  = (const float*)d_in[5];
    const float* wdcn = (const float*)d_in[6];
    const float* bdcn = (const float*)d_in[7];
    float* out = (float*)d_out;

    const size_t NH_B  = (size_t)BB * HWSZ * 128 * 2;     // 16,777,216
    const size_t OFF_B = (size_t)BB * HWSZ * 64 * 2;      //  8,388,608
    const size_t GM_B  = (size_t)BB * HWSZ * 64 * 2 + 64; // + overread pad
    const size_t WF1_B = 36 * 4 * 512 * 2;                //    147,456
    const size_t WF2_B = 18 * 14 * 512 * 2;               //    258,048

    char* ws = (char*)d_ws;
    unsigned short* nhwcin = (unsigned short*)ws;
    unsigned short* off_f  = (unsigned short*)(ws + NH_B);
    unsigned short* gm     = (unsigned short*)(ws + NH_B + OFF_B);
    unsigned short* wf1    = (unsigned short*)(ws + NH_B + OFF_B + GM_B);
    unsigned short* wf2    = wf1 + WF1_B / 2;
    unsigned short* wdf    = wf2 + WF2_B / 2;

    // 1) prep: transpose (NHWC128 bf16 + fp16 gm) and all weight repacks
    prep_kernel<<<1024 + 936, 256, 0, stream>>>(
        nbr, ref, w1, wom, wdcn, nhwcin, gm, wf1, wf2, wdf);

    // 2) conv1: 128ch -> 64ch + lrelu, NHWC bf16
    conv_mfma_kernel<128, NF, true, 2><<<512, 256, 0, stream>>>(
        nhwcin, wf1, b1, off_f);

    // 3) fused conv_om + deformable conv (32-px blocks, 2 waves, full-K)
    dcn_fused_kernel<<<2048, 128, 0, stream>>>(
        off_f, gm, wf2, bom, wdf, bdcn, out);
}

// Round 10
// 95.884 us; speedup vs baseline: 1.6080x; 1.2985x over previous
//
#include <hip/hip_runtime.h>
#include <hip/hip_bf16.h>
#include <hip/hip_fp16.h>
#include <cmath>

#define NF 64
#define GRP 8
#define CG 8
#define KK 9
#define HH 128
#define WWID 128
#define BB 4
#define HWSZ (HH * WWID)
#define C_OM 216
#define OMS 292   // om LDS px-stride in halfs
#define DPS 72    // staged-row px-stride in halfs (64ch + 8 pad)

typedef __attribute__((ext_vector_type(8))) short bf16x8;
typedef __attribute__((ext_vector_type(8))) _Float16 f16x8;
typedef __attribute__((ext_vector_type(4))) float f32x4;

__device__ inline unsigned short f2bf(float f) {
    union { float f; unsigned u; } x; x.f = f;
    unsigned r = x.u + 0x7fff + ((x.u >> 16) & 1);   // RNE
    return (unsigned short)(r >> 16);
}

// ---------------------------------------------------------------------------
// PREP: blocks 0..1023 = NCHW fp32 (nbr++ref) -> NHWC bf16 [B][H][W][128]
//       + group-major FP16 gather buffer gm[B][G][H][W][8].
//       blocks 1024+   = weight repacks (wf1 bf16, wf2 bf16, wdf fp16).
// ---------------------------------------------------------------------------
__global__ __launch_bounds__(256) void prep_kernel(
    const float* __restrict__ nbr, const float* __restrict__ ref,
    const float* __restrict__ w1, const float* __restrict__ wom,
    const float* __restrict__ wdcn,
    unsigned short* __restrict__ out, unsigned short* __restrict__ gm,
    unsigned short* __restrict__ wf1, unsigned short* __restrict__ wf2,
    unsigned short* __restrict__ wdf)
{
    __shared__ unsigned short lds[64 * 136];
    __shared__ __half lds_h[64 * 72];
    const int tid = threadIdx.x;

    if (blockIdx.x < 1024) {
        const int blk = blockIdx.x;
        const int b = blk >> 8, rem = blk & 255, y = rem >> 1, x0 = (rem & 1) * 64;
        const size_t rowoff = (size_t)y * WWID + x0;

        for (int it = 0; it < 32; ++it) {
            int idx = it * 256 + tid;
            int c = idx >> 6, p = idx & 63;
            const float* src = (c < NF) ? (nbr + (size_t)(b * NF + c) * HWSZ)
                                        : (ref + (size_t)(b * NF + c - NF) * HWSZ);
            const float v = src[rowoff + p];
            lds[p * 136 + c] = f2bf(v);
            if (c < 64) lds_h[p * 72 + c] = __float2half(v);
        }
        __syncthreads();
        const int p = tid >> 2, c0 = (tid & 3) * 32;
        unsigned short* dst = out + ((size_t)b * HWSZ + rowoff + p) * 128 + c0;
#pragma unroll
        for (int i = 0; i < 8; ++i)
            *(int2*)(dst + i * 4) = *(const int2*)&lds[p * 136 + c0 + i * 4];
        if (c0 < 64) {
#pragma unroll
            for (int gi = 0; gi < 4; ++gi) {
                const int g = (c0 >> 3) + gi;
                *(int4*)(gm + (((size_t)(b * 8 + g)) * HWSZ + rowoff + p) * 8) =
                    *(const int4*)&lds_h[p * 72 + g * 8];
            }
        }
        return;
    }

    int idx = (blockIdx.x - 1024) * 256 + tid;
    if (idx < 73728) {                 // conv1 A-frags [36][4][64][8] bf16
        int j = idx & 7, lane = (idx >> 3) & 63, t = idx >> 9;
        int mt = t % 4, kt = t / 4;
        int c0 = (kt / 9) * 32, tap = kt - (kt / 9) * 9;
        int cout = mt * 16 + (lane & 15);
        int cin = c0 + ((lane >> 4) * 8) + j;
        wf1[idx] = f2bf(w1[((size_t)cout * 128 + cin) * KK + tap]);
        return;
    }
    idx -= 73728;
    if (idx < 129024) {                // om A-frags [18][14][64][8] bf16
        int j = idx & 7, lane = (idx >> 3) & 63, t = idx >> 9;
        int mt = t % 14, kt = t / 14;
        int c0 = (kt / 9) * 32, tap = kt - (kt / 9) * 9;
        int cout = mt * 16 + (lane & 15);
        int cin = c0 + ((lane >> 4) * 8) + j;
        float v = (cout < C_OM) ? wom[((size_t)cout * 64 + cin) * KK + tap] : 0.f;
        wf2[idx] = f2bf(v);
        return;
    }
    idx -= 129024;
    if (idx < 36864) {                 // dcn A-frags [18][4][64][8] fp16
        int j = idx & 7, lane = (idx >> 3) & 63, t = idx >> 9;
        int mt = t & 3, s = t >> 2;
        int cout = mt * 16 + (lane & 15);
        int kglob = s * 32 + (lane >> 4) * 8 + j;
        int gk = kglob >> 3, c = kglob & 7;
        int g = gk / 9, kt = gk - g * 9;
        const __half hv = __float2half(wdcn[((size_t)cout * NF + g * 8 + c) * 9 + kt]);
        wdf[idx] = *(const unsigned short*)&hv;
    }
}

// ---------------------------------------------------------------------------
// conv1 (128ch -> 64ch, 3x3, lrelu) with LDS row staging.
// Block = 256 thr / 4 waves sharing one 64-px segment; waves split couts.
// Stages 3 rows x 66 px x 64 ch at a time (two channel-halves).
// ---------------------------------------------------------------------------
__global__ __launch_bounds__(256) void conv1_kernel(
    const unsigned short* __restrict__ in,   // NHWC bf16 [B][H][W][128]
    const unsigned short* __restrict__ wf,   // A-frags [36][4][64][8]
    const float* __restrict__ bias,
    unsigned short* __restrict__ dst)        // NHWC bf16 [B][H][W][64]
{
    __shared__ unsigned short st[3 * 66 * DPS];   // 28,512 B

    const int tid = threadIdx.x;
    const int lane = tid & 63;
    const int wv = tid >> 6;
    const int ng = blockIdx.x;
    const int b = ng >> 8, rem = ng & 255;
    const int y = rem >> 1, x0 = (rem & 1) * 64;
    const int ln = lane & 15, kb = lane >> 4;

    f32x4 acc[4];
#pragma unroll
    for (int nt = 0; nt < 4; ++nt) acc[nt] = f32x4{0.f, 0.f, 0.f, 0.f};

    for (int ch0 = 0; ch0 < 128; ch0 += 64) {
        __syncthreads();
        for (int i = tid; i < 3 * 66 * 8; i += 256) {
            const int j = i & 7, t = i >> 3;
            const int px = t % 66, r = t / 66;
            const int yy = y + r - 1, xx = x0 + px - 1;
            int4 v = {0, 0, 0, 0};
            if ((unsigned)yy < (unsigned)HH && (unsigned)xx < (unsigned)WWID)
                v = *(const int4*)(in + ((size_t)b * HWSZ + yy * WWID + xx) * 128
                                      + ch0 + j * 8);
            *(int4*)&st[(r * 66 + px) * DPS + j * 8] = v;
        }
        __syncthreads();

#pragma unroll
        for (int cc = 0; cc < 64; cc += 32) {
#pragma unroll
            for (int tap = 0; tap < 9; ++tap) {
                const int ky = tap / 3, kx = tap % 3;
                const int kt = ((ch0 + cc) / 32) * 9 + tap;
                const bf16x8 afrag =
                    *(const bf16x8*)(wf + (((size_t)kt * 4 + wv) * 64 + lane) * 8);
                bf16x8 bfrag[4];
#pragma unroll
                for (int nt = 0; nt < 4; ++nt) {
                    const int px = nt * 16 + ln + kx;   // slot = gx - (x0-1)
                    bfrag[nt] = *(const bf16x8*)&st[(ky * 66 + px) * DPS + cc + kb * 8];
                }
#pragma unroll
                for (int nt = 0; nt < 4; ++nt)
                    acc[nt] = __builtin_amdgcn_mfma_f32_16x16x32_bf16(
                        afrag, bfrag[nt], acc[nt], 0, 0, 0);
            }
        }
    }

    const int cout = wv * 16 + kb * 4;
    const float b0 = bias[cout], b1 = bias[cout + 1];
    const float b2 = bias[cout + 2], b3 = bias[cout + 3];
#pragma unroll
    for (int nt = 0; nt < 4; ++nt) {
        const int px = x0 + nt * 16 + ln;
        const size_t pix = (size_t)b * HWSZ + (size_t)y * WWID + px;
        f32x4 v = acc[nt];
        v[0] += b0; v[1] += b1; v[2] += b2; v[3] += b3;
#pragma unroll
        for (int r = 0; r < 4; ++r) v[r] = (v[r] >= 0.f) ? v[r] : 0.1f * v[r];
        int2 pk;
        pk.x = (int)f2bf(v[0]) | ((int)f2bf(v[1]) << 16);
        pk.y = (int)f2bf(v[2]) | ((int)f2bf(v[3]) << 16);
        *(int2*)(dst + pix * 64 + cout) = pk;
    }
}

// ---------------------------------------------------------------------------
// FUSED conv_om + DCN. Block = 256 thr / 4 waves / 64 px, grid 1024.
// Stage:     off_f rows (3 x 66 x 64ch) -> LDS (union with om quads).
// Phase 1:   om[216][64] GEMM, B from LDS, A split 4/4/3/3 across waves.
// Epilogue:  om -> LDS fp16 (oy,ox,mr,pad) quads (overwrites stage).
// Phase 1.5: in-place sigmoid of mr.
// Phase 2:   wave = 16 px full K; FP16 group-major gathers; packed
//            v_pk_fma_f16 interpolation; f16 MFMA. (R8-identical)
// ---------------------------------------------------------------------------
__global__ __launch_bounds__(256, 4) void dcn_fused_kernel(
    const unsigned short* __restrict__ off_f,   // NHWC bf16 [B][H][W][64]
    const unsigned short* __restrict__ gm,      // gmajor FP16 [B][G][H][W][8]
    const unsigned short* __restrict__ wf2,     // om A-frags bf16 (MT=14)
    const float* __restrict__ bom,
    const unsigned short* __restrict__ wdf,     // dcn A-frags FP16
    const float* __restrict__ bdcn,
    float* __restrict__ out)
{
    __shared__ unsigned short smem[64 * OMS];   // 37,376 B (stage/om union)

    const int raw = blockIdx.x;                 // 0..1023
    const int bid = (raw & 7) * 128 + (raw >> 3);   // XCD-contiguous
    const int b = bid >> 8;
    const int rem = bid & 255;
    const int y = rem >> 1;
    const int x0 = (rem & 1) * 64;

    const int tid = threadIdx.x;
    const int lane = tid & 63;
    const int wv = tid >> 6;                    // 0..3
    const int ln = lane & 15, kb = lane >> 4;

    // ---------------- Stage off_f rows into LDS ---------------------------
    for (int i = tid; i < 3 * 66 * 8; i += 256) {
        const int j = i & 7, t = i >> 3;
        const int px = t % 66, r = t / 66;
        const int yy = y + r - 1, xx = x0 + px - 1;
        int4 v = {0, 0, 0, 0};
        if ((unsigned)yy < (unsigned)HH && (unsigned)xx < (unsigned)WWID)
            v = *(const int4*)(off_f + ((size_t)b * HWSZ + yy * WWID + xx) * 64 + j * 8);
        *(int4*)&smem[(r * 66 + px) * DPS + j * 8] = v;
    }
    __syncthreads();

    // ---------------- Phase 1: om GEMM (M=224 pad, N=64, K=576) -----------
    f32x4 acc1[4][4];
#pragma unroll
    for (int i = 0; i < 4; ++i)
#pragma unroll
        for (int j = 0; j < 4; ++j) acc1[i][j] = f32x4{0.f, 0.f, 0.f, 0.f};

#pragma unroll
    for (int cc = 0; cc < 64; cc += 32) {
#pragma unroll
        for (int tap = 0; tap < 9; ++tap) {
            const int ky = tap / 3, kx = tap % 3;
            const int kt = (cc / 32) * 9 + tap;
            bf16x8 bfrag[4];
#pragma unroll
            for (int nt = 0; nt < 4; ++nt) {
                const int px = nt * 16 + ln + kx;
                bfrag[nt] = *(const bf16x8*)&smem[(ky * 66 + px) * DPS + cc + kb * 8];
            }
            const bf16x8* af = (const bf16x8*)wf2 + (size_t)kt * 14 * 64 + lane;
#pragma unroll
            for (int i = 0; i < 4; ++i) {
                const int mt = wv + 4 * i;
                if (mt < 14) {
                    bf16x8 a = af[(size_t)mt * 64];
#pragma unroll
                    for (int nt = 0; nt < 4; ++nt)
                        acc1[i][nt] = __builtin_amdgcn_mfma_f32_16x16x32_bf16(
                            a, bfrag[nt], acc1[i][nt], 0, 0, 0);
                }
            }
        }
    }
    __syncthreads();    // all stage reads done; smem may be overwritten

    // ---------------- om epilogue -> LDS fp16 quads ------------------------
    __half* smh = (__half*)smem;
#pragma unroll
    for (int i = 0; i < 4; ++i) {
        const int mt = wv + 4 * i;
        if (mt >= 14) continue;
        const int cb = mt * 16 + kb * 4;
#pragma unroll
        for (int nt = 0; nt < 4; ++nt) {
            const int px = nt * 16 + ln;
#pragma unroll
            for (int r = 0; r < 4; ++r) {
                const int c = cb + r;
                if (c < C_OM) {
                    const int field = (c >= 144) ? 2 : ((c >= 72) ? 1 : 0);
                    const int gk = c - field * 72;
                    smh[px * OMS + gk * 4 + field] =
                        __float2half(acc1[i][nt][r] + bom[c]);
                }
            }
        }
    }
    __syncthreads();

    // ---------------- Phase 1.5: in-place sigmoid of mr --------------------
    {
        const int px = tid & 63;
        const int g0 = (tid >> 6) * 18;          // 4 slices of 18 gk
        __half* base = &smh[px * OMS];
#pragma unroll
        for (int i = 0; i < 18; ++i) {
            const int gk = g0 + i;
            const float mr = __half2float(base[gk * 4 + 2]);
            base[gk * 4 + 2] = __float2half(1.f / (1.f + __expf(-mr)));
        }
    }
    __syncthreads();

    // ---------------- Phase 2: sampling + einsum (full K per wave) ---------
    const int pxl = wv * 16 + ln;      // 0..63
    const int x = x0 + pxl;

    f32x4 acc[4];
#pragma unroll
    for (int mt = 0; mt < 4; ++mt) acc[mt] = f32x4{0.f, 0.f, 0.f, 0.f};

    const unsigned short* gmb = gm + (size_t)b * 8 * HWSZ * 8;

#pragma unroll
    for (int ch = 0; ch < 3; ++ch) {
        short4 q[6];
#pragma unroll
        for (int i = 0; i < 6; ++i) {
            const int gk = (ch * 6 + i) * 4 + kb;
            q[i] = *(const short4*)&smh[pxl * OMS + gk * 4];
        }

#pragma unroll
        for (int i = 0; i < 6; ++i) {
            const int s = ch * 6 + i;
            const int gk = s * 4 + kb;
            const int g = gk / 9;
            const int kt = gk - g * 9;

            const float oy = __half2float(((const __half*)&q[i])[0]);
            const float ox = __half2float(((const __half*)&q[i])[1]);
            const float mv = __half2float(((const __half*)&q[i])[2]);

            const float pyf = (float)(y + kt / 3 - 1) + oy;
            const float pxf = (float)(x + kt % 3 - 1) + ox;
            const float fy = floorf(pyf), fx = floorf(pxf);
            const float wy = pyf - fy, wx = pxf - fx;
            const int iy = (int)fy, ix = (int)fx;

            float w00 = (1.f - wy) * (1.f - wx);
            float w01 = (1.f - wy) * wx;
            float w10 = wy * (1.f - wx);
            float w11 = wy * wx;

            const bool vy0 = (iy >= 0) && (iy < HH);
            const bool vy1 = (iy + 1 >= 0) && (iy + 1 < HH);
            const bool vx0 = (ix >= 0) && (ix < WWID);
            const bool vx1 = (ix + 1 >= 0) && (ix + 1 < WWID);
            w00 *= (vy0 && vx0) ? mv : 0.f;
            w01 *= (vy0 && vx1) ? mv : 0.f;
            w10 *= (vy1 && vx0) ? mv : 0.f;
            w11 *= (vy1 && vx1) ? mv : 0.f;

            const int y0c = min(max(iy, 0), HH - 1);
            const int y1c = min(max(iy + 1, 0), HH - 1);
            const int x0c = min(max(ix, 0), WWID - 1);
            const int x1c = min(max(ix + 1, 0), WWID - 1);
            const int sel = x1c - x0c;

            const float wl0 = w00 + (sel ? 0.f : w01);
            const float wh0 = sel ? w01 : 0.f;
            const float wl1 = w10 + (sel ? 0.f : w11);
            const float wh1 = sel ? w11 : 0.f;

            const unsigned short* pgm = gmb + (size_t)g * HWSZ * 8;
            const size_t rec0 = (size_t)(y0c * WWID + x0c) * 8;
            const size_t rec1 = (size_t)(y1c * WWID + x0c) * 8;
            int4 L0 = *(const int4*)(pgm + rec0);
            int4 H0 = *(const int4*)(pgm + rec0 + 8);
            int4 L1 = *(const int4*)(pgm + rec1);
            int4 H1 = *(const int4*)(pgm + rec1 + 8);

            const __half2 wl0h = __float2half2_rn(wl0);
            const __half2 wh0h = __float2half2_rn(wh0);
            const __half2 wl1h = __float2half2_rn(wl1);
            const __half2 wh1h = __float2half2_rn(wh1);
            const __half2* l0 = (const __half2*)&L0;
            const __half2* h0 = (const __half2*)&H0;
            const __half2* l1 = (const __half2*)&L1;
            const __half2* h1 = (const __half2*)&H1;
            __half2 bp0 = __hfma2(l0[0], wl0h, __hfma2(h0[0], wh0h,
                          __hfma2(l1[0], wl1h, __hmul2(h1[0], wh1h))));
            __half2 bp1 = __hfma2(l0[1], wl0h, __hfma2(h0[1], wh0h,
                          __hfma2(l1[1], wl1h, __hmul2(h1[1], wh1h))));
            __half2 bp2 = __hfma2(l0[2], wl0h, __hfma2(h0[2], wh0h,
                          __hfma2(l1[2], wl1h, __hmul2(h1[2], wh1h))));
            __half2 bp3 = __hfma2(l0[3], wl0h, __hfma2(h0[3], wh0h,
                          __hfma2(l1[3], wl1h, __hmul2(h1[3], wh1h))));
            __half2 bpv[4] = {bp0, bp1, bp2, bp3};
            const f16x8 bfrag = *(const f16x8*)bpv;

            const f16x8* af = (const f16x8*)wdf + ((size_t)s * 4) * 64 + lane;
#pragma unroll
            for (int mt = 0; mt < 4; ++mt)
                acc[mt] = __builtin_amdgcn_mfma_f32_16x16x32_f16(
                    af[(size_t)mt * 64], bfrag, acc[mt], 0, 0, 0);
        }
    }

    // ---------------- Epilogue: direct store -------------------------------
#pragma unroll
    for (int mt = 0; mt < 4; ++mt) {
#pragma unroll
        for (int r = 0; r < 4; ++r) {
            const int cout = mt * 16 + kb * 4 + r;
            float v = acc[mt][r] + bdcn[cout];
            v = (v >= 0.f) ? v : 0.1f * v;
            out[((size_t)(b * NF + cout)) * HWSZ + (size_t)y * WWID + x] = v;
        }
    }
}

// ---------------------------------------------------------------------------
extern "C" void kernel_launch(void* const* d_in, const int* in_sizes, int n_in,
                              void* d_out, int out_size, void* d_ws, size_t ws_size,
                              hipStream_t stream)
{
    const float* nbr  = (const float*)d_in[0];
    const float* ref  = (const float*)d_in[1];
    const float* w1   = (const float*)d_in[2];
    const float* b1   = (const float*)d_in[3];
    const float* wom  = (const float*)d_in[4];
    const float* bom  = (const float*)d_in[5];
    const float* wdcn = (const float*)d_in[6];
    const float* bdcn = (const float*)d_in[7];
    float* out = (float*)d_out;

    const size_t NH_B  = (size_t)BB * HWSZ * 128 * 2;     // 16,777,216
    const size_t OFF_B = (size_t)BB * HWSZ * 64 * 2;      //  8,388,608
    const size_t GM_B  = (size_t)BB * HWSZ * 64 * 2 + 64; // + overread pad
    const size_t WF1_B = 36 * 4 * 512 * 2;                //    147,456
    const size_t WF2_B = 18 * 14 * 512 * 2;               //    258,048

    char* ws = (char*)d_ws;
    unsigned short* nhwcin = (unsigned short*)ws;
    unsigned short* off_f  = (unsigned short*)(ws + NH_B);
    unsigned short* gm     = (unsigned short*)(ws + NH_B + OFF_B);
    unsigned short* wf1    = (unsigned short*)(ws + NH_B + OFF_B + GM_B);
    unsigned short* wf2    = wf1 + WF1_B / 2;
    unsigned short* wdf    = wf2 + WF2_B / 2;

    // 1) prep: transpose (NHWC128 bf16 + fp16 gm) and all weight repacks
    prep_kernel<<<1024 + 936, 256, 0, stream>>>(
        nbr, ref, w1, wom, wdcn, nhwcin, gm, wf1, wf2, wdf);

    // 2) conv1: staged-LDS implicit GEMM, 64-px blocks
    conv1_kernel<<<1024, 256, 0, stream>>>(nhwcin, wf1, b1, off_f);

    // 3) fused conv_om + deformable conv (64-px blocks, 4 waves)
    dcn_fused_kernel<<<1024, 256, 0, stream>>>(
        off_f, gm, wf2, bom, wdf, bdcn, out);
}